// Round 21
// baseline (201.676 us; speedup 1.0000x reference)
//
#include <hip/hip_runtime.h>

#define NNODES 65536
#define FIN 1024
#define NEDGES 2097152
#define NB 64
#define G 256
#define SCATB 1024            // scatter blocks (dispatched first)
#define CH2 (NEDGES / SCATB)  // 2048 edges per scatter block
#define CAPR 32               // slots per (bucket, blk) cell (mean 8, +8.5 sigma)
#define CAPB 9216
#define SCAP 10240
#define XRG 772               // x region stride: /4 mod 8 = 1 -> quad spread
#define XSR 12                // x row stride (8 k + 4 pad)
#define WRG 132               // w region stride: /4 mod 8 = 1

// ====== kernel A: scatter (blocks 0..1023) ∪ gemm h1 = x@W1 (blocks 1024..2047) ======
union ASMem {
  struct { float sx[8 * XRG]; float sw[8 * WRG]; } g;                           // 28.9 KB
  struct { int2 ent[CH2]; int hist[256], excl[256], cursor[256], sh[256]; } s;  // 20.4 KB
};

__global__ __launch_bounds__(256) void kfusedA(const float* __restrict__ x, const float* __restrict__ W1,
                                               float* __restrict__ h1, const int* __restrict__ src,
                                               const int* __restrict__ dst, const float* __restrict__ ew,
                                               int2* __restrict__ tmp, int* __restrict__ counts) {
  __shared__ ASMem sm;
  const int t = threadIdx.x;
  if (blockIdx.x < SCATB) {
    // ---------------- scatter: 2048 edges, LDS-staged, contiguous cell writes ----------------
    const int blk = blockIdx.x;
    const int base = blk * CH2;
    sm.s.hist[t] = 0;
    __syncthreads();
    int sa[8], da[8]; float wa[8];
#pragma unroll
    for (int i = 0; i < 8; ++i) {
      const int e = base + t + i * 256;
      sa[i] = src[e]; da[i] = dst[e]; wa[i] = ew[e];
      atomicAdd(&sm.s.hist[((unsigned)da[i]) >> 8], 1);
    }
    __syncthreads();
    sm.s.sh[t] = sm.s.hist[t];
    __syncthreads();
#pragma unroll
    for (int off = 1; off < 256; off <<= 1) {
      int a = (t >= off) ? sm.s.sh[t - off] : 0;
      __syncthreads();
      sm.s.sh[t] += a;
      __syncthreads();
    }
    {
      const int e = sm.s.sh[t] - sm.s.hist[t];
      sm.s.excl[t] = e;
      sm.s.cursor[t] = e;
      counts[t * SCATB + blk] = sm.s.hist[t];   // cell = bucket*1024 + blk
    }
    __syncthreads();
#pragma unroll
    for (int i = 0; i < 8; ++i) {
      const int b = ((unsigned)da[i]) >> 8;
      const int pos = atomicAdd(&sm.s.cursor[b], 1);
      sm.s.ent[pos] = make_int2((sa[i] & 0xFFFF) | ((da[i] & 255) << 16) | (b << 24),
                                __float_as_int(wa[i]));
    }
    __syncthreads();
#pragma unroll
    for (int i = 0; i < 8; ++i) {
      const int idx = t + i * 256;
      const int2 p = sm.s.ent[idx];
      const int b = ((unsigned)p.x) >> 24;
      const int local = idx - sm.s.excl[b];
      if (local < CAPR)
        tmp[(size_t)(b * SCATB + blk) * CAPR + local] = make_int2(p.x & 0x00FFFFFF, p.y);
    }
  } else {
    // ---------------- gemm (R19 verified body) ----------------
    const int jg2 = t & 1, ks = (t >> 1) & 7, rg = t >> 4;
    const int row0 = (blockIdx.x - SCATB) * 64;
    float4 accA[4], accB[4];
#pragma unroll
    for (int ri = 0; ri < 4; ++ri) {
      accA[ri] = make_float4(0.f, 0.f, 0.f, 0.f);
      accB[ri] = make_float4(0.f, 0.f, 0.f, 0.f);
    }
    for (int ch = 0; ch < 16; ++ch) {
      const int c0 = ch * 64;
#pragma unroll
      for (int i = 0; i < 4; ++i) {
        const int v = t + i * 256;
        const int rr = v >> 4, kq = v & 15;
        *(float4*)&sm.g.sx[(kq >> 1) * XRG + rr * XSR + (kq & 1) * 4] =
            *(const float4*)(x + (size_t)(row0 + rr) * FIN + c0 + kq * 4);
      }
      {
        const int kr = t >> 2, c4 = t & 3;
        *(float4*)&sm.g.sw[(kr >> 3) * WRG + (kr & 7) * 16 + c4 * 4] =
            *(const float4*)(W1 + (size_t)(c0 + kr) * 16 + c4 * 4);
      }
      __syncthreads();
      const int xb = ks * XRG + rg * (4 * XSR);
      const int wb = ks * WRG + jg2 * 8;
#pragma unroll
      for (int k4 = 0; k4 < 2; ++k4) {
        float4 x4[4];
#pragma unroll
        for (int ri = 0; ri < 4; ++ri) x4[ri] = *(const float4*)&sm.g.sx[xb + ri * XSR + k4 * 4];
#pragma unroll
        for (int kqi = 0; kqi < 4; ++kqi) {
          const float4 wa = *(const float4*)&sm.g.sw[wb + (k4 * 4 + kqi) * 16];
          const float4 wbv = *(const float4*)&sm.g.sw[wb + (k4 * 4 + kqi) * 16 + 4];
          const float xs0 = (kqi == 0) ? x4[0].x : (kqi == 1) ? x4[0].y : (kqi == 2) ? x4[0].z : x4[0].w;
          const float xs1 = (kqi == 0) ? x4[1].x : (kqi == 1) ? x4[1].y : (kqi == 2) ? x4[1].z : x4[1].w;
          const float xs2 = (kqi == 0) ? x4[2].x : (kqi == 1) ? x4[2].y : (kqi == 2) ? x4[2].z : x4[2].w;
          const float xs3 = (kqi == 0) ? x4[3].x : (kqi == 1) ? x4[3].y : (kqi == 2) ? x4[3].z : x4[3].w;
          accA[0].x = fmaf(xs0, wa.x, accA[0].x); accA[0].y = fmaf(xs0, wa.y, accA[0].y);
          accA[0].z = fmaf(xs0, wa.z, accA[0].z); accA[0].w = fmaf(xs0, wa.w, accA[0].w);
          accB[0].x = fmaf(xs0, wbv.x, accB[0].x); accB[0].y = fmaf(xs0, wbv.y, accB[0].y);
          accB[0].z = fmaf(xs0, wbv.z, accB[0].z); accB[0].w = fmaf(xs0, wbv.w, accB[0].w);
          accA[1].x = fmaf(xs1, wa.x, accA[1].x); accA[1].y = fmaf(xs1, wa.y, accA[1].y);
          accA[1].z = fmaf(xs1, wa.z, accA[1].z); accA[1].w = fmaf(xs1, wa.w, accA[1].w);
          accB[1].x = fmaf(xs1, wbv.x, accB[1].x); accB[1].y = fmaf(xs1, wbv.y, accB[1].y);
          accB[1].z = fmaf(xs1, wbv.z, accB[1].z); accB[1].w = fmaf(xs1, wbv.w, accB[1].w);
          accA[2].x = fmaf(xs2, wa.x, accA[2].x); accA[2].y = fmaf(xs2, wa.y, accA[2].y);
          accA[2].z = fmaf(xs2, wa.z, accA[2].z); accA[2].w = fmaf(xs2, wa.w, accA[2].w);
          accB[2].x = fmaf(xs2, wbv.x, accB[2].x); accB[2].y = fmaf(xs2, wbv.y, accB[2].y);
          accB[2].z = fmaf(xs2, wbv.z, accB[2].z); accB[2].w = fmaf(xs2, wbv.w, accB[2].w);
          accA[3].x = fmaf(xs3, wa.x, accA[3].x); accA[3].y = fmaf(xs3, wa.y, accA[3].y);
          accA[3].z = fmaf(xs3, wa.z, accA[3].z); accA[3].w = fmaf(xs3, wa.w, accA[3].w);
          accB[3].x = fmaf(xs3, wbv.x, accB[3].x); accB[3].y = fmaf(xs3, wbv.y, accB[3].y);
          accB[3].z = fmaf(xs3, wbv.z, accB[3].z); accB[3].w = fmaf(xs3, wbv.w, accB[3].w);
        }
      }
      __syncthreads();
    }
#pragma unroll
    for (int off = 2; off <= 8; off <<= 1) {
#pragma unroll
      for (int ri = 0; ri < 4; ++ri) {
        accA[ri].x += __shfl_xor(accA[ri].x, off, 64);
        accA[ri].y += __shfl_xor(accA[ri].y, off, 64);
        accA[ri].z += __shfl_xor(accA[ri].z, off, 64);
        accA[ri].w += __shfl_xor(accA[ri].w, off, 64);
        accB[ri].x += __shfl_xor(accB[ri].x, off, 64);
        accB[ri].y += __shfl_xor(accB[ri].y, off, 64);
        accB[ri].z += __shfl_xor(accB[ri].z, off, 64);
        accB[ri].w += __shfl_xor(accB[ri].w, off, 64);
      }
    }
    if (ks == 0) {
#pragma unroll
      for (int ri = 0; ri < 4; ++ri) {
        float* hp = h1 + (size_t)(row0 + rg * 4 + ri) * 16 + jg2 * 8;
        *(float4*)hp = accA[ri];
        *(float4*)(hp + 4) = accB[ri];
      }
    }
  }
}

// ========== kernel B: fine sort + dinv + in-place h1 prescale (1 thr/cell, 1024 cells) =====
__global__ __launch_bounds__(1024) void ksortE(const int2* __restrict__ tmp, const int* __restrict__ counts,
                                               int2* __restrict__ csr, int* __restrict__ rs,
                                               int* __restrict__ cnt, float* __restrict__ dinv,
                                               float* __restrict__ h1) {
  __shared__ int2 stg[SCAP];
  __shared__ int hist[256], excl[256], cursor[256];
  __shared__ float degacc[256], dloc[256];
  const int t = threadIdx.x, b = blockIdx.x;
  const int len = counts[b * SCATB + t];    // 1 thread per cell
  const size_t cellbase = (size_t)(b * SCATB + t) * CAPR;
  if (t < 256) { hist[t] = 0; degacc[t] = 0.f; }
  __syncthreads();
  for (int i = 0; i < len; ++i) {
    const int2 p = tmp[cellbase + i];
    const int fine = (p.x >> 16) & 255;
    atomicAdd(&hist[fine], 1);
    atomicAdd(&degacc[fine], __int_as_float(p.y));
  }
  __syncthreads();
  if (t < 256) excl[t] = hist[t];
  __syncthreads();
#pragma unroll
  for (int off = 1; off < 256; off <<= 1) {
    int a = (t < 256 && t >= off) ? excl[t - off] : 0;
    __syncthreads();
    if (t < 256) excl[t] += a;
    __syncthreads();
  }
  if (t < 256) {
    const int e = excl[t] - hist[t];
    cursor[t] = e;
    rs[b * 256 + t] = b * CAPB + e;
    cnt[b * 256 + t] = hist[t];
    const float dn = rsqrtf(1.0f + degacc[t]);
    dloc[t] = dn;
    dinv[b * 256 + t] = dn;
  }
  __syncthreads();
  for (int i = 0; i < len; ++i) {
    const int2 p = tmp[cellbase + i];
    const int fine = (p.x >> 16) & 255;
    const int pos = atomicAdd(&cursor[fine], 1);
    const int2 rec = make_int2(p.x & 0xFFFF, p.y);
    if (pos < SCAP) stg[pos] = rec;
    else csr[(size_t)b * CAPB + pos] = rec;
  }
  __syncthreads();
  const int ntot = excl[255];
  for (int j = t; j < ntot; j += 1024) csr[(size_t)b * CAPB + j] = stg[j];
  {
    const int node = t >> 2, q = t & 3;
    float* hp = h1 + (size_t)(b * 256 + node) * 16 + q * 4;
    float4 h = *(float4*)hp;
    const float dn = dloc[node];
    h.x *= dn; h.y *= dn; h.z *= dn; h.w *= dn;
    *(float4*)hp = h;
  }
}

// ====== gather layer 1: 2 nodes/wave (32 lanes each: 8 slots x float4), csr prefetch ======
__global__ __launch_bounds__(256) void kgather1(const float* __restrict__ H1, const int* __restrict__ rs,
                                                const int* __restrict__ cnt, const int2* __restrict__ csr,
                                                const float* __restrict__ dinv,
                                                const float* __restrict__ W2, const float* __restrict__ b1,
                                                float* __restrict__ H2) {
  __shared__ float sh_t[8][16];
  const int tid = threadIdx.x, wv = tid >> 6, l = tid & 63;
  const int half = l >> 5, ll = l & 31;
  const int n = blockIdx.x * 8 + wv * 2 + half;
  const int f4 = ll & 3, slot = ll >> 2;    // 8 slots x 4 lanes per node
  const int beg = rs[n], len = cnt[n];
  float4 acc = make_float4(0.f, 0.f, 0.f, 0.f);
  int2 pcur;
  if (slot < len) pcur = csr[beg + slot];
  for (int j = slot; j < len; j += 8) {
    const int jn = j + 8;
    int2 pnext;
    if (jn < len) pnext = csr[beg + jn];    // prefetch overlaps gather below
    const float w = __int_as_float(pcur.y);
    const float4 hv = *(const float4*)(H1 + (size_t)pcur.x * 16 + f4 * 4);
    acc.x = fmaf(w, hv.x, acc.x);
    acc.y = fmaf(w, hv.y, acc.y);
    acc.z = fmaf(w, hv.z, acc.z);
    acc.w = fmaf(w, hv.w, acc.w);
    pcur = pnext;
  }
#pragma unroll
  for (int off = 4; off < 32; off <<= 1) {  // reduce within the 32-lane half
    acc.x += __shfl_xor(acc.x, off, 64);
    acc.y += __shfl_xor(acc.y, off, 64);
    acc.z += __shfl_xor(acc.z, off, 64);
    acc.w += __shfl_xor(acc.w, off, 64);
  }
  if (slot == 0) {
    const float dn = dinv[n];
    const float4 hs = *(const float4*)(H1 + (size_t)n * 16 + f4 * 4);
    float t0 = dn * (acc.x + hs.x) + b1[f4 * 4 + 0];
    float t1 = dn * (acc.y + hs.y) + b1[f4 * 4 + 1];
    float t2 = dn * (acc.z + hs.z) + b1[f4 * 4 + 2];
    float t3 = dn * (acc.w + hs.w) + b1[f4 * 4 + 3];
    sh_t[wv * 2 + half][f4 * 4 + 0] = t0 > 0.f ? t0 : 0.f;
    sh_t[wv * 2 + half][f4 * 4 + 1] = t1 > 0.f ? t1 : 0.f;
    sh_t[wv * 2 + half][f4 * 4 + 2] = t2 > 0.f ? t2 : 0.f;
    sh_t[wv * 2 + half][f4 * 4 + 3] = t3 > 0.f ? t3 : 0.f;
  }
  __syncthreads();
  if (tid < 32) {
    const int w2 = tid >> 2, c = tid & 3;
    const int nn = blockIdx.x * 8 + w2;
    float s = 0.f;
#pragma unroll
    for (int ff = 0; ff < 16; ++ff) s = fmaf(sh_t[w2][ff], W2[ff * 4 + c], s);
    H2[(size_t)nn * 4 + c] = s * dinv[nn];
  }
}

// ============ gather layer 2 ============
__global__ __launch_bounds__(256) void kgather2(const float* __restrict__ H2, const int* __restrict__ rs,
                                                const int* __restrict__ cnt, const int2* __restrict__ csr,
                                                const float* __restrict__ dinv,
                                                const float* __restrict__ W3, const float* __restrict__ b2,
                                                float* __restrict__ H3) {
  const int tid = threadIdx.x, wv = tid >> 6, l = tid & 63;
  const int n = blockIdx.x * 4 + wv;
  const int f = l & 3, slot = l >> 2;
  const int beg = rs[n], len = cnt[n];
  float acc = 0.f;
  for (int j = slot; j < len; j += 16) {
    const int2 p = csr[beg + j];
    acc = fmaf(__int_as_float(p.y), H2[(size_t)p.x * 4 + f], acc);
  }
#pragma unroll
  for (int off = 4; off < 64; off <<= 1) acc += __shfl_xor(acc, off, 64);
  const float dn = dinv[n];
  float t = dn * (acc + H2[(size_t)n * 4 + f]) + b2[f];
  t = t > 0.f ? t : 0.f;
  float p = t * W3[f];
  p += __shfl_xor(p, 1, 64);
  p += __shfl_xor(p, 2, 64);
  if (l == 0) H3[n] = p * dn;
}

// ============ gather layer 3 (+ seed out with bias) ============
__global__ __launch_bounds__(256) void kgather3(const float* __restrict__ H3, const int* __restrict__ rs,
                                                const int* __restrict__ cnt, const int2* __restrict__ csr,
                                                const float* __restrict__ dinv,
                                                const float* __restrict__ b3, float* __restrict__ flat,
                                                const float* __restrict__ bout, float* __restrict__ out) {
  const int tid = threadIdx.x, wv = tid >> 6, l = tid & 63;
  if (blockIdx.x == 0 && tid < NB) out[tid] = bout[tid];
  const int n = blockIdx.x * 4 + wv;
  const int beg = rs[n], len = cnt[n];
  float acc = 0.f;
  for (int j = l; j < len; j += 64) {
    const int2 p = csr[beg + j];
    acc = fmaf(__int_as_float(p.y), H3[p.x], acc);
  }
#pragma unroll
  for (int off = 1; off < 64; off <<= 1) acc += __shfl_xor(acc, off, 64);
  if (l == 0) {
    const float dn = dinv[n];
    float t = dn * (acc + H3[n]) + b3[0];
    flat[n] = t > 0.f ? t : 0.f;
  }
}

// ============ final dense: out[b] += partial dot (atomic) ============
__global__ __launch_bounds__(256) void kfinal(const float* __restrict__ flat, const float* __restrict__ Wout,
                                              float* __restrict__ out) {
  const int b = blockIdx.x >> 4, q = blockIdx.x & 15;
  const float4* __restrict__ f4 = (const float4*)(flat) + q * 1024;
  const float4* __restrict__ w4 = (const float4*)(Wout + (size_t)b * NNODES) + q * 1024;
  __shared__ float red[4];
  float s = 0.f;
  for (int i = threadIdx.x; i < 1024; i += 256) {
    const float4 a = f4[i];
    const float4 wv = w4[i];
    s += a.x * wv.x + a.y * wv.y + a.z * wv.z + a.w * wv.w;
  }
#pragma unroll
  for (int off = 32; off; off >>= 1) s += __shfl_down(s, off, 64);
  if ((threadIdx.x & 63) == 0) red[threadIdx.x >> 6] = s;
  __syncthreads();
  if (threadIdx.x == 0) atomicAdd(&out[b], red[0] + red[1] + red[2] + red[3]);
}

extern "C" void kernel_launch(void* const* d_in, const int* in_sizes, int n_in,
                              void* d_out, int out_size, void* d_ws, size_t ws_size,
                              hipStream_t stream) {
  const float* x   = (const float*)d_in[0];
  const int*   A   = (const int*)d_in[1];
  const float* ew  = (const float*)d_in[2];
  const float* W1  = (const float*)d_in[3];
  const float* b1  = (const float*)d_in[4];
  const float* W2  = (const float*)d_in[5];
  const float* b2  = (const float*)d_in[6];
  const float* W3  = (const float*)d_in[7];
  const float* b3  = (const float*)d_in[8];
  const float* Wo  = (const float*)d_in[9];
  const float* bo  = (const float*)d_in[10];
  float* out = (float*)d_out;

  const int* src = A;
  const int* dst = A + NEDGES;

  // ---- workspace layout (~90 MB of ~1 GB ws) ----
  char* p = (char*)d_ws;
  float* dinv   = (float*)p; p += sizeof(float) * NNODES;
  int*   rsofs  = (int*)p;   p += sizeof(int) * NNODES;
  int*   cnt    = (int*)p;   p += sizeof(int) * NNODES;
  int*   counts = (int*)p;   p += sizeof(int) * G * SCATB;                 // 1 MB
  int2*  tmp    = (int2*)p;  p += sizeof(int2) * (size_t)G * SCATB * CAPR; // 64 MB
  int2*  csr    = (int2*)p;  p += sizeof(int2) * (size_t)G * CAPB;         // 18.9 MB
  float* h1     = (float*)p; p += sizeof(float) * (size_t)NNODES * 16;
  float* H2     = (float*)p; p += sizeof(float) * (size_t)NNODES * 4;
  float* H3     = (float*)p; p += sizeof(float) * NNODES;
  float* flat   = (float*)p; p += sizeof(float) * NNODES;

  kfusedA<<<SCATB + NNODES / 64, 256, 0, stream>>>(x, W1, h1, src, dst, ew, tmp, counts);
  ksortE<<<G, 1024, 0, stream>>>(tmp, counts, csr, rsofs, cnt, dinv, h1);
  kgather1<<<NNODES / 8, 256, 0, stream>>>(h1, rsofs, cnt, csr, dinv, W2, b1, H2);
  kgather2<<<NNODES / 4, 256, 0, stream>>>(H2, rsofs, cnt, csr, dinv, W3, b2, H3);
  kgather3<<<NNODES / 4, 256, 0, stream>>>(H3, rsofs, cnt, csr, dinv, b3, flat, bo, out);
  kfinal<<<NB * 16, 256, 0, stream>>>(flat, Wo, out);
}

// Round 23
// 186.118 us; speedup vs baseline: 1.0836x; 1.0836x over previous
//
#include <hip/hip_runtime.h>

#define NNODES 65536
#define FIN 1024
#define NEDGES 2097152
#define NB 64
#define G 256
#define SCATB 512             // scatter blocks (dispatched first)
#define CH2 (NEDGES / SCATB)  // 4096 edges per scatter block
#define CAPR 48               // slots per (bucket, blk) cell (mean 16, 8 sigma)
#define CAPB 9216
#define SCAP 10240
#define XRG 772               // x region stride: /4 mod 8 = 1 -> quad spread
#define XSR 12                // x row stride (8 k + 4 pad)
#define WRG 132               // w region stride: /4 mod 8 = 1

// ====== kernel A: scatter (blocks 0..511) ∪ gemm h1 = x@W1 (blocks 512..1535) — R20 ======
union ASMem {
  struct { float sx[8 * XRG]; float sw[8 * WRG]; } g;                     // 28.9 KB
  struct { int2 ent[CH2]; int hist[256], excl[256], cursor[256], sh[256]; } s;  // 36.9 KB
};

__global__ __launch_bounds__(256) void kfusedA(const float* __restrict__ x, const float* __restrict__ W1,
                                               float* __restrict__ h1, const int* __restrict__ src,
                                               const int* __restrict__ dst, const float* __restrict__ ew,
                                               int2* __restrict__ tmp, int* __restrict__ counts) {
  __shared__ ASMem sm;
  const int t = threadIdx.x;
  if (blockIdx.x < SCATB) {
    // ---------------- scatter: 4096 edges, LDS-staged, contiguous cell writes ----------------
    const int blk = blockIdx.x;
    const int base = blk * CH2;
    sm.s.hist[t] = 0;
    __syncthreads();
    int sa[16], da[16]; float wa[16];
#pragma unroll
    for (int i = 0; i < 16; ++i) {
      const int e = base + t + i * 256;
      sa[i] = src[e]; da[i] = dst[e]; wa[i] = ew[e];
      atomicAdd(&sm.s.hist[((unsigned)da[i]) >> 8], 1);
    }
    __syncthreads();
    sm.s.sh[t] = sm.s.hist[t];
    __syncthreads();
#pragma unroll
    for (int off = 1; off < 256; off <<= 1) {
      int a = (t >= off) ? sm.s.sh[t - off] : 0;
      __syncthreads();
      sm.s.sh[t] += a;
      __syncthreads();
    }
    {
      const int e = sm.s.sh[t] - sm.s.hist[t];
      sm.s.excl[t] = e;
      sm.s.cursor[t] = e;
      counts[t * SCATB + blk] = sm.s.hist[t];   // cell = bucket*512 + blk
    }
    __syncthreads();
#pragma unroll
    for (int i = 0; i < 16; ++i) {
      const int b = ((unsigned)da[i]) >> 8;
      const int pos = atomicAdd(&sm.s.cursor[b], 1);
      sm.s.ent[pos] = make_int2((sa[i] & 0xFFFF) | ((da[i] & 255) << 16) | (b << 24),
                                __float_as_int(wa[i]));
    }
    __syncthreads();
#pragma unroll
    for (int i = 0; i < 16; ++i) {
      const int idx = t + i * 256;
      const int2 p = sm.s.ent[idx];
      const int b = ((unsigned)p.x) >> 24;
      const int local = idx - sm.s.excl[b];
      if (local < CAPR)
        tmp[(size_t)(b * SCATB + blk) * CAPR + local] = make_int2(p.x & 0x00FFFFFF, p.y);
    }
  } else {
    // ---------------- gemm (R19 verified body) ----------------
    const int jg2 = t & 1, ks = (t >> 1) & 7, rg = t >> 4;
    const int row0 = (blockIdx.x - SCATB) * 64;
    float4 accA[4], accB[4];
#pragma unroll
    for (int ri = 0; ri < 4; ++ri) {
      accA[ri] = make_float4(0.f, 0.f, 0.f, 0.f);
      accB[ri] = make_float4(0.f, 0.f, 0.f, 0.f);
    }
    for (int ch = 0; ch < 16; ++ch) {
      const int c0 = ch * 64;
#pragma unroll
      for (int i = 0; i < 4; ++i) {
        const int v = t + i * 256;
        const int rr = v >> 4, kq = v & 15;
        *(float4*)&sm.g.sx[(kq >> 1) * XRG + rr * XSR + (kq & 1) * 4] =
            *(const float4*)(x + (size_t)(row0 + rr) * FIN + c0 + kq * 4);
      }
      {
        const int kr = t >> 2, c4 = t & 3;
        *(float4*)&sm.g.sw[(kr >> 3) * WRG + (kr & 7) * 16 + c4 * 4] =
            *(const float4*)(W1 + (size_t)(c0 + kr) * 16 + c4 * 4);
      }
      __syncthreads();
      const int xb = ks * XRG + rg * (4 * XSR);
      const int wb = ks * WRG + jg2 * 8;
#pragma unroll
      for (int k4 = 0; k4 < 2; ++k4) {
        float4 x4[4];
#pragma unroll
        for (int ri = 0; ri < 4; ++ri) x4[ri] = *(const float4*)&sm.g.sx[xb + ri * XSR + k4 * 4];
#pragma unroll
        for (int kqi = 0; kqi < 4; ++kqi) {
          const float4 wa = *(const float4*)&sm.g.sw[wb + (k4 * 4 + kqi) * 16];
          const float4 wbv = *(const float4*)&sm.g.sw[wb + (k4 * 4 + kqi) * 16 + 4];
          const float xs0 = (kqi == 0) ? x4[0].x : (kqi == 1) ? x4[0].y : (kqi == 2) ? x4[0].z : x4[0].w;
          const float xs1 = (kqi == 0) ? x4[1].x : (kqi == 1) ? x4[1].y : (kqi == 2) ? x4[1].z : x4[1].w;
          const float xs2 = (kqi == 0) ? x4[2].x : (kqi == 1) ? x4[2].y : (kqi == 2) ? x4[2].z : x4[2].w;
          const float xs3 = (kqi == 0) ? x4[3].x : (kqi == 1) ? x4[3].y : (kqi == 2) ? x4[3].z : x4[3].w;
          accA[0].x = fmaf(xs0, wa.x, accA[0].x); accA[0].y = fmaf(xs0, wa.y, accA[0].y);
          accA[0].z = fmaf(xs0, wa.z, accA[0].z); accA[0].w = fmaf(xs0, wa.w, accA[0].w);
          accB[0].x = fmaf(xs0, wbv.x, accB[0].x); accB[0].y = fmaf(xs0, wbv.y, accB[0].y);
          accB[0].z = fmaf(xs0, wbv.z, accB[0].z); accB[0].w = fmaf(xs0, wbv.w, accB[0].w);
          accA[1].x = fmaf(xs1, wa.x, accA[1].x); accA[1].y = fmaf(xs1, wa.y, accA[1].y);
          accA[1].z = fmaf(xs1, wa.z, accA[1].z); accA[1].w = fmaf(xs1, wa.w, accA[1].w);
          accB[1].x = fmaf(xs1, wbv.x, accB[1].x); accB[1].y = fmaf(xs1, wbv.y, accB[1].y);
          accB[1].z = fmaf(xs1, wbv.z, accB[1].z); accB[1].w = fmaf(xs1, wbv.w, accB[1].w);
          accA[2].x = fmaf(xs2, wa.x, accA[2].x); accA[2].y = fmaf(xs2, wa.y, accA[2].y);
          accA[2].z = fmaf(xs2, wa.z, accA[2].z); accA[2].w = fmaf(xs2, wa.w, accA[2].w);
          accB[2].x = fmaf(xs2, wbv.x, accB[2].x); accB[2].y = fmaf(xs2, wbv.y, accB[2].y);
          accB[2].z = fmaf(xs2, wbv.z, accB[2].z); accB[2].w = fmaf(xs2, wbv.w, accB[2].w);
          accA[3].x = fmaf(xs3, wa.x, accA[3].x); accA[3].y = fmaf(xs3, wa.y, accA[3].y);
          accA[3].z = fmaf(xs3, wa.z, accA[3].z); accA[3].w = fmaf(xs3, wa.w, accA[3].w);
          accB[3].x = fmaf(xs3, wbv.x, accB[3].x); accB[3].y = fmaf(xs3, wbv.y, accB[3].y);
          accB[3].z = fmaf(xs3, wbv.z, accB[3].z); accB[3].w = fmaf(xs3, wbv.w, accB[3].w);
        }
      }
      __syncthreads();
    }
#pragma unroll
    for (int off = 2; off <= 8; off <<= 1) {
#pragma unroll
      for (int ri = 0; ri < 4; ++ri) {
        accA[ri].x += __shfl_xor(accA[ri].x, off, 64);
        accA[ri].y += __shfl_xor(accA[ri].y, off, 64);
        accA[ri].z += __shfl_xor(accA[ri].z, off, 64);
        accA[ri].w += __shfl_xor(accA[ri].w, off, 64);
        accB[ri].x += __shfl_xor(accB[ri].x, off, 64);
        accB[ri].y += __shfl_xor(accB[ri].y, off, 64);
        accB[ri].z += __shfl_xor(accB[ri].z, off, 64);
        accB[ri].w += __shfl_xor(accB[ri].w, off, 64);
      }
    }
    if (ks == 0) {
#pragma unroll
      for (int ri = 0; ri < 4; ++ri) {
        float* hp = h1 + (size_t)(row0 + rg * 4 + ri) * 16 + jg2 * 8;
        *(float4*)hp = accA[ri];
        *(float4*)(hp + 4) = accB[ri];
      }
    }
  }
}

// ========== kernel B: fine sort + dinv + in-place h1 prescale (2 thr/cell, 512 cells) ======
__global__ __launch_bounds__(1024) void ksortE(const int2* __restrict__ tmp, const int* __restrict__ counts,
                                               int2* __restrict__ csr, int* __restrict__ rs,
                                               int* __restrict__ cnt, float* __restrict__ dinv,
                                               float* __restrict__ h1) {
  __shared__ int2 stg[SCAP];
  __shared__ int hist[256], excl[256], cursor[256];
  __shared__ float degacc[256], dloc[256];
  const int t = threadIdx.x, b = blockIdx.x;
  const int seg = t >> 1, q2 = t & 1;       // 2 threads per cell, 512 cells
  const int len = counts[b * SCATB + seg];
  const size_t cellbase = (size_t)(b * SCATB + seg) * CAPR;
  if (t < 256) { hist[t] = 0; degacc[t] = 0.f; }
  __syncthreads();
  for (int i = q2; i < len; i += 2) {
    const int2 p = tmp[cellbase + i];
    const int fine = (p.x >> 16) & 255;
    atomicAdd(&hist[fine], 1);
    atomicAdd(&degacc[fine], __int_as_float(p.y));
  }
  __syncthreads();
  if (t < 256) excl[t] = hist[t];
  __syncthreads();
#pragma unroll
  for (int off = 1; off < 256; off <<= 1) {
    int a = (t < 256 && t >= off) ? excl[t - off] : 0;
    __syncthreads();
    if (t < 256) excl[t] += a;
    __syncthreads();
  }
  if (t < 256) {
    const int e = excl[t] - hist[t];
    cursor[t] = e;
    rs[b * 256 + t] = b * CAPB + e;
    cnt[b * 256 + t] = hist[t];
    const float dn = rsqrtf(1.0f + degacc[t]);
    dloc[t] = dn;
    dinv[b * 256 + t] = dn;
  }
  __syncthreads();
  for (int i = q2; i < len; i += 2) {
    const int2 p = tmp[cellbase + i];
    const int fine = (p.x >> 16) & 255;
    const int pos = atomicAdd(&cursor[fine], 1);
    const int2 rec = make_int2(p.x & 0xFFFF, p.y);
    if (pos < SCAP) stg[pos] = rec;
    else csr[(size_t)b * CAPB + pos] = rec;
  }
  __syncthreads();
  const int ntot = excl[255];
  for (int j = t; j < ntot; j += 1024) csr[(size_t)b * CAPB + j] = stg[j];
  {
    const int node = t >> 2, q = t & 3;
    float* hp = h1 + (size_t)(b * 256 + node) * 16 + q * 4;
    float4 h = *(float4*)hp;
    const float dn = dloc[node];
    h.x *= dn; h.y *= dn; h.z *= dn; h.w *= dn;
    *(float4*)hp = h;
  }
}

// ====== gather layer 1: 2 nodes/wave (32 lanes each: 8 slots x float4), csr prefetch ======
__global__ __launch_bounds__(256) void kgather1(const float* __restrict__ H1, const int* __restrict__ rs,
                                                const int* __restrict__ cnt, const int2* __restrict__ csr,
                                                const float* __restrict__ dinv,
                                                const float* __restrict__ W2, const float* __restrict__ b1,
                                                float* __restrict__ H2) {
  __shared__ float sh_t[8][16];
  const int tid = threadIdx.x, wv = tid >> 6, l = tid & 63;
  const int half = l >> 5, ll = l & 31;
  const int n = blockIdx.x * 8 + wv * 2 + half;
  const int f4 = ll & 3, slot = ll >> 2;    // 8 slots x 4 lanes per node
  const int beg = rs[n], len = cnt[n];
  float4 acc = make_float4(0.f, 0.f, 0.f, 0.f);
  int2 pcur;
  if (slot < len) pcur = csr[beg + slot];
  for (int j = slot; j < len; j += 8) {
    const int jn = j + 8;
    int2 pnext;
    if (jn < len) pnext = csr[beg + jn];    // prefetch overlaps gather below
    const float w = __int_as_float(pcur.y);
    const float4 hv = *(const float4*)(H1 + (size_t)pcur.x * 16 + f4 * 4);
    acc.x = fmaf(w, hv.x, acc.x);
    acc.y = fmaf(w, hv.y, acc.y);
    acc.z = fmaf(w, hv.z, acc.z);
    acc.w = fmaf(w, hv.w, acc.w);
    pcur = pnext;
  }
#pragma unroll
  for (int off = 4; off < 32; off <<= 1) {  // reduce within the 32-lane half
    acc.x += __shfl_xor(acc.x, off, 64);
    acc.y += __shfl_xor(acc.y, off, 64);
    acc.z += __shfl_xor(acc.z, off, 64);
    acc.w += __shfl_xor(acc.w, off, 64);
  }
  if (slot == 0) {
    const float dn = dinv[n];
    const float4 hs = *(const float4*)(H1 + (size_t)n * 16 + f4 * 4);
    float t0 = dn * (acc.x + hs.x) + b1[f4 * 4 + 0];
    float t1 = dn * (acc.y + hs.y) + b1[f4 * 4 + 1];
    float t2 = dn * (acc.z + hs.z) + b1[f4 * 4 + 2];
    float t3 = dn * (acc.w + hs.w) + b1[f4 * 4 + 3];
    sh_t[wv * 2 + half][f4 * 4 + 0] = t0 > 0.f ? t0 : 0.f;
    sh_t[wv * 2 + half][f4 * 4 + 1] = t1 > 0.f ? t1 : 0.f;
    sh_t[wv * 2 + half][f4 * 4 + 2] = t2 > 0.f ? t2 : 0.f;
    sh_t[wv * 2 + half][f4 * 4 + 3] = t3 > 0.f ? t3 : 0.f;
  }
  __syncthreads();
  if (tid < 32) {
    const int w2 = tid >> 2, c = tid & 3;
    const int nn = blockIdx.x * 8 + w2;
    float s = 0.f;
#pragma unroll
    for (int ff = 0; ff < 16; ++ff) s = fmaf(sh_t[w2][ff], W2[ff * 4 + c], s);
    H2[(size_t)nn * 4 + c] = s * dinv[nn];
  }
}

// ============ gather layer 2 ============
__global__ __launch_bounds__(256) void kgather2(const float* __restrict__ H2, const int* __restrict__ rs,
                                                const int* __restrict__ cnt, const int2* __restrict__ csr,
                                                const float* __restrict__ dinv,
                                                const float* __restrict__ W3, const float* __restrict__ b2,
                                                float* __restrict__ H3) {
  const int tid = threadIdx.x, wv = tid >> 6, l = tid & 63;
  const int n = blockIdx.x * 4 + wv;
  const int f = l & 3, slot = l >> 2;
  const int beg = rs[n], len = cnt[n];
  float acc = 0.f;
  for (int j = slot; j < len; j += 16) {
    const int2 p = csr[beg + j];
    acc = fmaf(__int_as_float(p.y), H2[(size_t)p.x * 4 + f], acc);
  }
#pragma unroll
  for (int off = 4; off < 64; off <<= 1) acc += __shfl_xor(acc, off, 64);
  const float dn = dinv[n];
  float t = dn * (acc + H2[(size_t)n * 4 + f]) + b2[f];
  t = t > 0.f ? t : 0.f;
  float p = t * W3[f];
  p += __shfl_xor(p, 1, 64);
  p += __shfl_xor(p, 2, 64);
  if (l == 0) H3[n] = p * dn;
}

// ============ gather layer 3 (+ seed out with bias) ============
__global__ __launch_bounds__(256) void kgather3(const float* __restrict__ H3, const int* __restrict__ rs,
                                                const int* __restrict__ cnt, const int2* __restrict__ csr,
                                                const float* __restrict__ dinv,
                                                const float* __restrict__ b3, float* __restrict__ flat,
                                                const float* __restrict__ bout, float* __restrict__ out) {
  const int tid = threadIdx.x, wv = tid >> 6, l = tid & 63;
  if (blockIdx.x == 0 && tid < NB) out[tid] = bout[tid];
  const int n = blockIdx.x * 4 + wv;
  const int beg = rs[n], len = cnt[n];
  float acc = 0.f;
  for (int j = l; j < len; j += 64) {
    const int2 p = csr[beg + j];
    acc = fmaf(__int_as_float(p.y), H3[p.x], acc);
  }
#pragma unroll
  for (int off = 1; off < 64; off <<= 1) acc += __shfl_xor(acc, off, 64);
  if (l == 0) {
    const float dn = dinv[n];
    float t = dn * (acc + H3[n]) + b3[0];
    flat[n] = t > 0.f ? t : 0.f;
  }
}

// ============ final dense: out[b] += partial dot (atomic) ============
__global__ __launch_bounds__(256) void kfinal(const float* __restrict__ flat, const float* __restrict__ Wout,
                                              float* __restrict__ out) {
  const int b = blockIdx.x >> 4, q = blockIdx.x & 15;
  const float4* __restrict__ f4 = (const float4*)(flat) + q * 1024;
  const float4* __restrict__ w4 = (const float4*)(Wout + (size_t)b * NNODES) + q * 1024;
  __shared__ float red[4];
  float s = 0.f;
  for (int i = threadIdx.x; i < 1024; i += 256) {
    const float4 a = f4[i];
    const float4 wv = w4[i];
    s += a.x * wv.x + a.y * wv.y + a.z * wv.z + a.w * wv.w;
  }
#pragma unroll
  for (int off = 32; off; off >>= 1) s += __shfl_down(s, off, 64);
  if ((threadIdx.x & 63) == 0) red[threadIdx.x >> 6] = s;
  __syncthreads();
  if (threadIdx.x == 0) atomicAdd(&out[b], red[0] + red[1] + red[2] + red[3]);
}

extern "C" void kernel_launch(void* const* d_in, const int* in_sizes, int n_in,
                              void* d_out, int out_size, void* d_ws, size_t ws_size,
                              hipStream_t stream) {
  const float* x   = (const float*)d_in[0];
  const int*   A   = (const int*)d_in[1];
  const float* ew  = (const float*)d_in[2];
  const float* W1  = (const float*)d_in[3];
  const float* b1  = (const float*)d_in[4];
  const float* W2  = (const float*)d_in[5];
  const float* b2  = (const float*)d_in[6];
  const float* W3  = (const float*)d_in[7];
  const float* b3  = (const float*)d_in[8];
  const float* Wo  = (const float*)d_in[9];
  const float* bo  = (const float*)d_in[10];
  float* out = (float*)d_out;

  const int* src = A;
  const int* dst = A + NEDGES;

  // ---- workspace layout ----
  char* p = (char*)d_ws;
  float* dinv   = (float*)p; p += sizeof(float) * NNODES;
  int*   rsofs  = (int*)p;   p += sizeof(int) * NNODES;
  int*   cnt    = (int*)p;   p += sizeof(int) * NNODES;
  int*   counts = (int*)p;   p += sizeof(int) * G * SCATB;
  int2*  tmp    = (int2*)p;  p += sizeof(int2) * (size_t)G * SCATB * CAPR;
  int2*  csr    = (int2*)p;  p += sizeof(int2) * (size_t)G * CAPB;
  float* h1     = (float*)p; p += sizeof(float) * (size_t)NNODES * 16;
  float* H2     = (float*)p; p += sizeof(float) * (size_t)NNODES * 4;
  float* H3     = (float*)p; p += sizeof(float) * NNODES;
  float* flat   = (float*)p; p += sizeof(float) * NNODES;

  kfusedA<<<SCATB + NNODES / 64, 256, 0, stream>>>(x, W1, h1, src, dst, ew, tmp, counts);
  ksortE<<<G, 1024, 0, stream>>>(tmp, counts, csr, rsofs, cnt, dinv, h1);
  kgather1<<<NNODES / 8, 256, 0, stream>>>(h1, rsofs, cnt, csr, dinv, W2, b1, H2);
  kgather2<<<NNODES / 4, 256, 0, stream>>>(H2, rsofs, cnt, csr, dinv, W3, b2, H3);
  kgather3<<<NNODES / 4, 256, 0, stream>>>(H3, rsofs, cnt, csr, dinv, b3, flat, bo, out);
  kfinal<<<NB * 16, 256, 0, stream>>>(flat, Wo, out);
}